// Round 10
// baseline (450.490 us; speedup 1.0000x reference)
//
#include <hip/hip_runtime.h>
#include <hip/hip_bf16.h>

typedef __bf16 bf16;
typedef bf16 bf16x2 __attribute__((ext_vector_type(2)));
typedef bf16 bf16x4 __attribute__((ext_vector_type(4)));
typedef bf16 bf16x8 __attribute__((ext_vector_type(8)));
typedef float f32x4 __attribute__((ext_vector_type(4)));
typedef float f32x16 __attribute__((ext_vector_type(16)));
typedef unsigned int u32;
typedef u32 u32x4 __attribute__((ext_vector_type(4)));

#define MFMA16(A,B,C) __builtin_amdgcn_mfma_f32_16x16x32_bf16(A,B,C,0,0,0)
#define MFMA32(A,B,C) __builtin_amdgcn_mfma_f32_32x32x16_bf16(A,B,C,0,0,0)

__device__ __forceinline__ void gld_lds16(const void* g, void* l) {
  __builtin_amdgcn_global_load_lds(
      (const __attribute__((address_space(1))) void*)g,
      (__attribute__((address_space(3))) void*)l, 16, 0, 0);
}

__device__ __forceinline__ float max3f(float a, float b, float c) {
  return fmaxf(fmaxf(a, b), c);   // clang fuses to v_max3_f32
}

// ---------------- fp32 -> bf16 casts (fused launches) ----------------
__global__ void cast3_kernel(const float* __restrict__ s0, const float* __restrict__ s1,
                             const float* __restrict__ s2,
                             bf16* __restrict__ d0, bf16* __restrict__ d1, bf16* __restrict__ d2) {
  const int which = blockIdx.x >> 13;
  const int i = (blockIdx.x & 8191) * 256 + threadIdx.x;
  const float* s = which == 0 ? s0 : which == 1 ? s1 : s2;
  bf16* d = which == 0 ? d0 : which == 1 ? d1 : d2;
  float4 v = ((const float4*)s)[i];
  bf16x4 o;
  o[0] = (bf16)v.x; o[1] = (bf16)v.y; o[2] = (bf16)v.z; o[3] = (bf16)v.w;
  *(bf16x4*)(d + (size_t)i * 4) = o;
}

__global__ void cast4_kernel(const float* __restrict__ s0, const float* __restrict__ s1,
                             const float* __restrict__ s2, const float* __restrict__ s3,
                             bf16* __restrict__ d0, bf16* __restrict__ d1,
                             bf16* __restrict__ d2, bf16* __restrict__ d3) {
  const int which = blockIdx.x >> 10;
  const int i = (blockIdx.x & 1023) * 256 + threadIdx.x;
  const float* s = which == 0 ? s0 : which == 1 ? s1 : which == 2 ? s2 : s3;
  bf16* d = which == 0 ? d0 : which == 1 ? d1 : which == 2 ? d2 : d3;
  float4 v = ((const float4*)s)[i];
  bf16x4 o;
  o[0] = (bf16)v.x; o[1] = (bf16)v.y; o[2] = (bf16)v.z; o[3] = (bf16)v.w;
  *(bf16x4*)(d + (size_t)i * 4) = o;
}

// mask(int 0/1) -> f32 additive (-1e9/0).
__global__ void maskf_kernel(const int* __restrict__ m, float* __restrict__ mf) {
  const int i = blockIdx.x * 256 + threadIdx.x;
  const int4 v = ((const int4*)m)[i];
  float4 o;
  o.x = v.x ? 0.0f : -1e9f;
  o.y = v.y ? 0.0f : -1e9f;
  o.z = v.z ? 0.0f : -1e9f;
  o.w = v.w ? 0.0f : -1e9f;
  ((float4*)mf)[i] = o;
}

// ---------------- 256x256 GEMM core, BK=32, K=1024, 2-phase-per-tile interleave ----
// 512 thr = 8 waves (2M x 4N), per-wave 128x64 (acc[8][4] = 128 VGPR).
// LDS: 3-slot ring (96 KB) — compute tile kt from slot kt%3, stage kt+2 into
// (kt+2)%3 (last read 2 tiles ago; R6-verified choreography). Tile-top publish:
// counted vmcnt(4) (tile kt's 4 loads retired; kt+1's stay in flight — never 0
// until the last tile) + barrier. Per K-tile 2 phases: {ds_read subtile, issue
// half of kt+2's stage, lgkmcnt(0), setprio(1) 16 MFMA setprio(0)} — the m196/m198
// fine interleave. Swizzle: R8-verified involution L = P ^ (((P>>7)&7)<<4);
// linear gld_lds dest + inverse-swizzled source; reads same XOR (2 lanes/slot, free).
__device__ __forceinline__ void gemm256_core(
    const bf16* __restrict__ aBase, const bf16* __restrict__ bBase,
    bf16* sA, bf16* sB, f32x4 (&acc)[8][4])
{
  const int t = threadIdx.x;
  const int lane = t & 63, w = t >> 6;
  const int wm = w >> 2, wn = w & 3;
  const int c = lane & 15, g = lane >> 4;

  const int P = t * 16;                       // dest byte within an 8KB round
  const int L = P ^ (((P >> 7) & 7) << 4);    // logical byte (involution)
  const int srow = L >> 6;                    // 0..127
  const int scol = (L & 63) >> 1;             // elem col 0/8/16/24

  auto stageA = [&](int slot, int kt) {
#pragma unroll
    for (int r = 0; r < 2; ++r)
      gld_lds16(aBase + (size_t)(r * 128 + srow) * 1024 + kt * 32 + scol,
                &sA[slot * 8192 + r * 4096 + t * 8]);
  };
  auto stageB = [&](int slot, int kt) {
#pragma unroll
    for (int r = 0; r < 2; ++r)
      gld_lds16(bBase + (size_t)(r * 128 + srow) * 1024 + kt * 32 + scol,
                &sB[slot * 8192 + r * 4096 + t * 8]);
  };
  auto rd = [&](const bf16* s, int row) -> bf16x8 {
    const int phys = (row * 64 + g * 16) ^ (((row >> 1) & 7) << 4);
    return *(const bf16x8*)((const char*)s + phys);
  };

  // prologue: tiles 0 and 1 in flight (8 loads/wave outstanding)
  stageA(0, 0); stageB(0, 0);
  stageA(1, 1); stageB(1, 1);

  int slot = 0;
#pragma unroll 1
  for (int kt = 0; kt < 32; ++kt) {
    int s2 = slot + 2; if (s2 >= 3) s2 -= 3;
    // ---- tile-top publish: counted vmcnt, then barrier ----
    if (kt < 31) asm volatile("s_waitcnt vmcnt(4)" ::: "memory");
    else         asm volatile("s_waitcnt vmcnt(0)" ::: "memory");
    __builtin_amdgcn_s_barrier();
    asm volatile("" ::: "memory");           // no LDS reads hoisted above publish

    const bf16* tA = sA + slot * 8192;
    const bf16* tB = sB + slot * 8192;

    // ---- phase 1: B frags + A rows 0-63, stage A-half of kt+2, MFMA quadrant ----
    bf16x8 bfr[4], af[4];
#pragma unroll
    for (int ni = 0; ni < 4; ++ni) bfr[ni] = rd(tB, wn * 64 + ni * 16 + c);
#pragma unroll
    for (int mi = 0; mi < 4; ++mi) af[mi] = rd(tA, wm * 128 + mi * 16 + c);
    if (kt < 30) stageA(s2, kt + 2);
    asm volatile("s_waitcnt lgkmcnt(0)" ::: "memory");
    __builtin_amdgcn_s_setprio(1);
#pragma unroll
    for (int mi = 0; mi < 4; ++mi)
#pragma unroll
      for (int ni = 0; ni < 4; ++ni)
        acc[mi][ni] = MFMA16(af[mi], bfr[ni], acc[mi][ni]);
    __builtin_amdgcn_s_setprio(0);
    __builtin_amdgcn_s_barrier();            // phase lockstep

    // ---- phase 2: A rows 64-127 (B reused from regs), stage B-half of kt+2 ----
#pragma unroll
    for (int mi = 0; mi < 4; ++mi) af[mi] = rd(tA, wm * 128 + (mi + 4) * 16 + c);
    if (kt < 30) stageB(s2, kt + 2);
    asm volatile("s_waitcnt lgkmcnt(0)" ::: "memory");
    __builtin_amdgcn_s_setprio(1);
#pragma unroll
    for (int mi = 0; mi < 4; ++mi)
#pragma unroll
      for (int ni = 0; ni < 4; ++ni)
        acc[mi + 4][ni] = MFMA16(af[mi], bfr[ni], acc[mi + 4][ni]);
    __builtin_amdgcn_s_setprio(0);

    slot += 1; if (slot >= 3) slot = 0;
  }
}

// QKV fused: grid (4, 32, 3) of 512 thr. z==2 writes V^T layout.
__global__ __launch_bounds__(512, 2) void qkv_gemm256(
    const bf16* __restrict__ qx, const bf16* __restrict__ kx, const bf16* __restrict__ vx,
    const bf16* __restrict__ wqb, const bf16* __restrict__ wkb, const bf16* __restrict__ wvb,
    const float* __restrict__ bq, const float* __restrict__ bk, const float* __restrict__ bv,
    bf16* __restrict__ qp, bf16* __restrict__ kp, bf16* __restrict__ vt, float qscale)
{
  __shared__ bf16 sA[3 * 8192];
  __shared__ bf16 sB[3 * 8192];
  const int z = blockIdx.z;
  const bf16* A    = z == 0 ? qx  : z == 1 ? kx  : vx;
  const bf16* Bm   = z == 0 ? wqb : z == 1 ? wkb : wvb;
  const float* bias = z == 0 ? bq : z == 1 ? bk : bv;
  const int bm = blockIdx.y, bn = blockIdx.x;

  f32x4 acc[8][4] = {};
  gemm256_core(A + (size_t)(bm * 256) * 1024, Bm + (size_t)(bn * 256) * 1024, sA, sB, acc);

  const int t = threadIdx.x, lane = t & 63, w = t >> 6;
  const int wm = w >> 2, wn = w & 3, c = lane & 15, g = lane >> 4;
  const float sc = z == 0 ? qscale : 1.0f;
  bf16* Cb = z == 0 ? qp : kp;
#pragma unroll
  for (int ni = 0; ni < 4; ++ni) {
    const int col = bn * 256 + wn * 64 + ni * 16 + c;
    const float bvv = bias[col];
#pragma unroll
    for (int mi = 0; mi < 8; ++mi) {
#pragma unroll
      for (int r4 = 0; r4 < 4; ++r4) {
        const int row = bm * 256 + wm * 128 + mi * 16 + g * 4 + r4;
        const float val = (acc[mi][ni][r4] + bvv) * sc;
        if (z == 2) {
          const int bb = row >> 11, s = row & 2047;
          vt[((size_t)(bb * 1024 + col)) * 2048 + s] = (bf16)val;
        } else {
          Cb[(size_t)row * 1024 + col] = (bf16)val;
        }
      }
    }
  }
}

// O-projection: f32 output. grid (4, 32).
__global__ __launch_bounds__(512, 2) void out_gemm256(
    const bf16* __restrict__ A, const bf16* __restrict__ Bm,
    const float* __restrict__ bias, float* __restrict__ Cout)
{
  __shared__ bf16 sA[3 * 8192];
  __shared__ bf16 sB[3 * 8192];
  const int bm = blockIdx.y, bn = blockIdx.x;

  f32x4 acc[8][4] = {};
  gemm256_core(A + (size_t)(bm * 256) * 1024, Bm + (size_t)(bn * 256) * 1024, sA, sB, acc);

  const int t = threadIdx.x, lane = t & 63, w = t >> 6;
  const int wm = w >> 2, wn = w & 3, c = lane & 15, g = lane >> 4;
#pragma unroll
  for (int ni = 0; ni < 4; ++ni) {
    const int col = bn * 256 + wn * 64 + ni * 16 + c;
    const float bvv = bias[col];
#pragma unroll
    for (int mi = 0; mi < 8; ++mi) {
#pragma unroll
      for (int r4 = 0; r4 < 4; ++r4) {
        const int row = bm * 256 + wm * 128 + mi * 16 + g * 4 + r4;
        Cout[(size_t)row * 1024 + col] = acc[mi][ni][r4] + bvv;
      }
    }
  }
}

// ---------------- flash attention (R9 structure; staging addresses hoisted) ------
__global__ __launch_bounds__(256) void attn_kernel(
    const bf16* __restrict__ Qp, const bf16* __restrict__ Kp, const bf16* __restrict__ Vt,
    const float* __restrict__ maskf, bf16* __restrict__ Out)
{
  __shared__ bf16 sKV[2][64 * 128];

  const int bh = blockIdx.x;
  const int b = bh >> 4, h = bh & 15;
  const int t = threadIdx.x, lane = t & 63, w = t >> 6;
  const int q32 = lane & 31, hi = lane >> 5;
  const int q0 = blockIdx.y * 128 + w * 32;

  const char* kBase = (const char*)(Kp + (size_t)(b * 2048) * 1024 + h * 64);
  const char* vBase = (const char*)(Vt + (size_t)(bh * 64) * 2048);

  // kt-uniform staging pointers: swizzle decode done ONCE; per-kt is 4 pointer adds.
  const char* srcp[4];
  int strd[4];
#pragma unroll
  for (int j = 0; j < 4; ++j) {
    const int P = j * 4096 + t * 16;
    const int L = P ^ (((P >> 8) & 15) << 4);
    const int row = L >> 8;          // 0..63
    const int off = L & 255;
    if (off < 128) { srcp[j] = kBase + (size_t)row * 2048 + off;         strd[j] = 131072; }
    else           { srcp[j] = vBase + (size_t)row * 4096 + (off - 128); strd[j] = 128; }
  }
  auto stageKV = [&](int buf) {
#pragma unroll
    for (int j = 0; j < 4; ++j)
      gld_lds16(srcp[j], (char*)sKV[buf] + j * 4096 + t * 16);
  };
  auto advKV = [&]() {
#pragma unroll
    for (int j = 0; j < 4; ++j) srcp[j] += strd[j];
  };

  bf16x8 qf[4];
  const bf16* qrow = Qp + (size_t)(b * 2048 + q0 + q32) * 1024 + h * 64;
#pragma unroll
  for (int ks = 0; ks < 4; ++ks)
    qf[ks] = *(const bf16x8*)&qrow[ks * 16 + hi * 8];

  float mrun = -1e30f, lrun = 0.f;
  f32x16 aco[2] = {};

  const float* mrow = maskf + b * 2048;

  stageKV(0);
  advKV();
  __syncthreads();
  int cur = 0;
  for (int kt = 0; kt < 32; ++kt) {
    if (kt + 1 < 32) { stageKV(cur ^ 1); advKV(); }

    // ---- S^T C-init = f32 additive mask (pure loads) ----
    f32x16 st[2];
#pragma unroll
    for (int kf = 0; kf < 2; ++kf)
#pragma unroll
      for (int q4 = 0; q4 < 4; ++q4) {
        const float4 mm = *(const float4*)&mrow[kt * 64 + kf * 32 + q4 * 8 + hi * 4];
        st[kf][q4 * 4 + 0] = mm.x;
        st[kf][q4 * 4 + 1] = mm.y;
        st[kf][q4 * 4 + 2] = mm.z;
        st[kf][q4 * 4 + 3] = mm.w;
      }

    // ---- S^T += K Q^T ----
#pragma unroll
    for (int ks = 0; ks < 4; ++ks) {
      bf16x8 k0f, k1f;
      {
        const int row = q32;
        const int phys = row * 256 + ((ks * 32 + hi * 16) ^ ((row & 15) << 4));
        k0f = *(const bf16x8*)((const char*)sKV[cur] + phys);
      }
      {
        const int row = 32 + q32;
        const int phys = row * 256 + ((ks * 32 + hi * 16) ^ ((row & 15) << 4));
        k1f = *(const bf16x8*)((const char*)sKV[cur] + phys);
      }
      __builtin_amdgcn_s_setprio(1);
      st[0] = MFMA32(k0f, qf[ks], st[0]);
      st[1] = MFMA32(k1f, qf[ks], st[1]);
      __builtin_amdgcn_s_setprio(0);
    }

    // ---- online softmax: max3 tree, defer-max, tree sum ----
    float c0 = max3f(st[0][0], st[0][1], st[0][2]);
    c0 = max3f(c0, st[0][3], st[0][4]);
    c0 = max3f(c0, st[0][5], st[0][6]);
    c0 = fmaxf(c0, st[0][7]);
    float c1 = max3f(st[0][8], st[0][9], st[0][10]);
    c1 = max3f(c1, st[0][11], st[0][12]);
    c1 = max3f(c1, st[0][13], st[0][14]);
    c1 = fmaxf(c1, st[0][15]);
    float c2 = max3f(st[1][0], st[1][1], st[1][2]);
    c2 = max3f(c2, st[1][3], st[1][4]);
    c2 = max3f(c2, st[1][5], st[1][6]);
    c2 = fmaxf(c2, st[1][7]);
    float c3 = max3f(st[1][8], st[1][9], st[1][10]);
    c3 = max3f(c3, st[1][11], st[1][12]);
    c3 = max3f(c3, st[1][13], st[1][14]);
    c3 = fmaxf(c3, st[1][15]);
    float tmax = fmaxf(max3f(c0, c1, c2), c3);
    tmax = fmaxf(tmax, __shfl_xor(tmax, 32, 64));
    if (!__all(tmax <= mrun + 11.5f)) {   // defer-max: THR = 8*log2(e)
      const float mnew = fmaxf(mrun, tmax);
      const float sc = exp2f(mrun - mnew);
      mrun = mnew;
      lrun *= sc;
      aco[0] *= sc;
      aco[1] *= sc;
    }
    float rs0 = 0.f, rs1 = 0.f, rs2 = 0.f, rs3 = 0.f;
#pragma unroll
    for (int i = 0; i < 16; i += 4) {
      float p00 = exp2f(st[0][i] - mrun),     p01 = exp2f(st[0][i + 1] - mrun);
      float p02 = exp2f(st[0][i + 2] - mrun), p03 = exp2f(st[0][i + 3] - mrun);
      float p10 = exp2f(st[1][i] - mrun),     p11 = exp2f(st[1][i + 1] - mrun);
      float p12 = exp2f(st[1][i + 2] - mrun), p13 = exp2f(st[1][i + 3] - mrun);
      st[0][i] = p00; st[0][i + 1] = p01; st[0][i + 2] = p02; st[0][i + 3] = p03;
      st[1][i] = p10; st[1][i + 1] = p11; st[1][i + 2] = p12; st[1][i + 3] = p13;
      rs0 += p00 + p01; rs1 += p02 + p03;
      rs2 += p10 + p11; rs3 += p12 + p13;
    }
    float rs = (rs0 + rs1) + (rs2 + rs3);
    rs += __shfl_xor(rs, 32, 64);
    lrun += rs;

    // ---- P -> PV A-frags in-register (T12) ----
    bf16x8 pa[4];
#pragma unroll
    for (int kf = 0; kf < 2; ++kf) {
      u32 u[4][2];
#pragma unroll
      for (int g2 = 0; g2 < 4; ++g2) {
        asm("v_cvt_pk_bf16_f32 %0, %1, %2"
            : "=v"(u[g2][0]) : "v"(st[kf][4 * g2 + 0]), "v"(st[kf][4 * g2 + 1]));
        asm("v_cvt_pk_bf16_f32 %0, %1, %2"
            : "=v"(u[g2][1]) : "v"(st[kf][4 * g2 + 2]), "v"(st[kf][4 * g2 + 3]));
      }
      u32 d0 = u[0][0], d2 = u[1][0];
      asm("v_permlane32_swap_b32 %0, %1" : "+v"(d0), "+v"(d2));
      u32 d1 = u[0][1], d3 = u[1][1];
      asm("v_permlane32_swap_b32 %0, %1" : "+v"(d1), "+v"(d3));
      u32x4 ud = {d0, d1, d2, d3};
      pa[2 * kf] = __builtin_bit_cast(bf16x8, ud);
      u32 e0 = u[2][0], e2 = u[3][0];
      asm("v_permlane32_swap_b32 %0, %1" : "+v"(e0), "+v"(e2));
      u32 e1 = u[2][1], e3 = u[3][1];
      asm("v_permlane32_swap_b32 %0, %1" : "+v"(e1), "+v"(e3));
      u32x4 ue = {e0, e1, e2, e3};
      pa[2 * kf + 1] = __builtin_bit_cast(bf16x8, ue);
    }

    // ---- O^T += V^T P^T ----
#pragma unroll
    for (int kk = 0; kk < 4; ++kk) {
      bf16x8 vb0, vb1;
      {
        const int row = q32;
        const int phys = row * 256 + ((128 + kk * 32 + hi * 16) ^ ((row & 15) << 4));
        vb0 = *(const bf16x8*)((const char*)sKV[cur] + phys);
      }
      {
        const int row = 32 + q32;
        const int phys = row * 256 + ((128 + kk * 32 + hi * 16) ^ ((row & 15) << 4));
        vb1 = *(const bf16x8*)((const char*)sKV[cur] + phys);
      }
      __builtin_amdgcn_s_setprio(1);
      aco[0] = MFMA32(vb0, pa[kk], aco[0]);
      aco[1] = MFMA32(vb1, pa[kk], aco[1]);
      __builtin_amdgcn_s_setprio(0);
    }

    __syncthreads();
    cur ^= 1;
  }

  const float inv = 1.0f / lrun;
  bf16* orow = Out + (size_t)(b * 2048 + q0 + q32) * 1024 + h * 64;
#pragma unroll
  for (int dkf = 0; dkf < 2; ++dkf)
#pragma unroll
    for (int q4 = 0; q4 < 4; ++q4) {
      bf16x4 o;
#pragma unroll
      for (int r4 = 0; r4 < 4; ++r4)
        o[r4] = (bf16)(aco[dkf][q4 * 4 + r4] * inv);
      *(bf16x4*)&orow[dkf * 32 + q4 * 8 + hi * 4] = o;
    }
}

extern "C" void kernel_launch(void* const* d_in, const int* in_sizes, int n_in,
                              void* d_out, int out_size, void* d_ws, size_t ws_size,
                              hipStream_t stream) {
  const float* q  = (const float*)d_in[0];
  const float* k  = (const float*)d_in[1];
  const float* v  = (const float*)d_in[2];
  const int*  msk = (const int*)d_in[3];
  const float* wq = (const float*)d_in[4];
  const float* bq = (const float*)d_in[5];
  const float* wk = (const float*)d_in[6];
  const float* bk = (const float*)d_in[7];
  const float* wv = (const float*)d_in[8];
  const float* bv = (const float*)d_in[9];
  const float* wo = (const float*)d_in[10];
  const float* bo = (const float*)d_in[11];

  bf16* ws = (bf16*)d_ws;
  const size_t NEL = 8192ull * 1024ull;  // 8M elements
  bf16* qx  = ws;
  bf16* kx  = ws + NEL;
  bf16* vx  = ws + 2 * NEL;
  bf16* wqb = ws + 3 * NEL;
  bf16* wkb = wqb + 1048576;
  bf16* wvb = wkb + 1048576;
  bf16* wob = wvb + 1048576;
  bf16* qp  = wob + 1048576;
  bf16* kp  = qp + NEL;
  bf16* vt  = kp + NEL;
  float* mf = (float*)(vt + NEL);        // 8192 f32 additive mask
  bf16* ao  = vx;  // vx dead after V projection

  cast3_kernel<<<24576, 256, 0, stream>>>(q, k, v, qx, kx, vx);
  cast4_kernel<<<4096, 256, 0, stream>>>(wq, wk, wv, wo, wqb, wkb, wvb, wob);
  maskf_kernel<<<8, 256, 0, stream>>>(msk, mf);

  // Q pre-scale folds softmax 1/sqrt(DK) AND log2(e) for exp2-domain softmax.
  const float qscale = 0.125f * 1.44269504088896f;
  qkv_gemm256<<<dim3(4, 32, 3), 512, 0, stream>>>(qx, kx, vx, wqb, wkb, wvb,
                                                  bq, bk, bv, qp, kp, vt, qscale);
  attn_kernel<<<dim3(64, 16), 256, 0, stream>>>(qp, kp, vt, mf, ao);
  out_gemm256<<<dim3(4, 32), 512, 0, stream>>>(ao, wob, bo, (float*)d_out);
}

// Round 11
// 424.845 us; speedup vs baseline: 1.0604x; 1.0604x over previous
//
#include <hip/hip_runtime.h>
#include <hip/hip_bf16.h>

typedef __bf16 bf16;
typedef bf16 bf16x2 __attribute__((ext_vector_type(2)));
typedef bf16 bf16x4 __attribute__((ext_vector_type(4)));
typedef bf16 bf16x8 __attribute__((ext_vector_type(8)));
typedef float f32x4 __attribute__((ext_vector_type(4)));
typedef float f32x16 __attribute__((ext_vector_type(16)));
typedef unsigned int u32;
typedef u32 u32x4 __attribute__((ext_vector_type(4)));

#define MFMA16(A,B,C) __builtin_amdgcn_mfma_f32_16x16x32_bf16(A,B,C,0,0,0)
#define MFMA32(A,B,C) __builtin_amdgcn_mfma_f32_32x32x16_bf16(A,B,C,0,0,0)

__device__ __forceinline__ void gld_lds16(const void* g, void* l) {
  __builtin_amdgcn_global_load_lds(
      (const __attribute__((address_space(1))) void*)g,
      (__attribute__((address_space(3))) void*)l, 16, 0, 0);
}

__device__ __forceinline__ float max3f(float a, float b, float c) {
  return fmaxf(fmaxf(a, b), c);   // clang fuses to v_max3_f32
}

// ---------------- fp32 -> bf16 casts (fused launches) ----------------
__global__ void cast3_kernel(const float* __restrict__ s0, const float* __restrict__ s1,
                             const float* __restrict__ s2,
                             bf16* __restrict__ d0, bf16* __restrict__ d1, bf16* __restrict__ d2) {
  const int which = blockIdx.x >> 13;
  const int i = (blockIdx.x & 8191) * 256 + threadIdx.x;
  const float* s = which == 0 ? s0 : which == 1 ? s1 : s2;
  bf16* d = which == 0 ? d0 : which == 1 ? d1 : d2;
  float4 v = ((const float4*)s)[i];
  bf16x4 o;
  o[0] = (bf16)v.x; o[1] = (bf16)v.y; o[2] = (bf16)v.z; o[3] = (bf16)v.w;
  *(bf16x4*)(d + (size_t)i * 4) = o;
}

__global__ void cast4_kernel(const float* __restrict__ s0, const float* __restrict__ s1,
                             const float* __restrict__ s2, const float* __restrict__ s3,
                             bf16* __restrict__ d0, bf16* __restrict__ d1,
                             bf16* __restrict__ d2, bf16* __restrict__ d3) {
  const int which = blockIdx.x >> 10;
  const int i = (blockIdx.x & 1023) * 256 + threadIdx.x;
  const float* s = which == 0 ? s0 : which == 1 ? s1 : which == 2 ? s2 : s3;
  bf16* d = which == 0 ? d0 : which == 1 ? d1 : which == 2 ? d2 : d3;
  float4 v = ((const float4*)s)[i];
  bf16x4 o;
  o[0] = (bf16)v.x; o[1] = (bf16)v.y; o[2] = (bf16)v.z; o[3] = (bf16)v.w;
  *(bf16x4*)(d + (size_t)i * 4) = o;
}

// mask(int 0/1) -> f32 additive (-1e9/0).
__global__ void maskf_kernel(const int* __restrict__ m, float* __restrict__ mf) {
  const int i = blockIdx.x * 256 + threadIdx.x;
  const int4 v = ((const int4*)m)[i];
  float4 o;
  o.x = v.x ? 0.0f : -1e9f;
  o.y = v.y ? 0.0f : -1e9f;
  o.z = v.z ? 0.0f : -1e9f;
  o.w = v.w ? 0.0f : -1e9f;
  ((float4*)mf)[i] = o;
}

// ---------------- 128x128 GEMM core (R9-proven: best measured GEMM config) --------
// 256 thr = 4 waves (2x2), per-wave 64x64 out, BK=32, K=1024, 32 KB LDS (~4 blk/CU).
// Counted vmcnt(4) across raw split barriers; R8-verified swizzle involution
// L = P ^ (((P>>7)&7)<<4): linear gld_lds dest + inverse-swizzled global source;
// frag reads apply the same XOR.
__device__ __forceinline__ void gemm128_core(
    const bf16* __restrict__ aBase, const bf16* __restrict__ bBase,
    bf16* sA, bf16* sB, f32x4 (&acc)[4][4])
{
  const int t = threadIdx.x;
  const int lane = t & 63, w = t >> 6;
  const int c = lane & 15, g = lane >> 4;

  int srow[2], scol[2];
#pragma unroll
  for (int i = 0; i < 2; ++i) {
    const int P = i * 4096 + t * 16;            // linear dest byte in 8KB tile
    const int L = P ^ (((P >> 7) & 7) << 4);    // logical byte (involution)
    srow[i] = L >> 6;                           // 0..127
    scol[i] = (L & 63) >> 1;                    // elem col 0/8/16/24
  }

  auto stage = [&](int buf, int kt) {
#pragma unroll
    for (int i = 0; i < 2; ++i)
      gld_lds16(aBase + (size_t)srow[i] * 1024 + kt * 32 + scol[i],
                &sA[buf * 4096 + i * 2048 + t * 8]);
#pragma unroll
    for (int i = 0; i < 2; ++i)
      gld_lds16(bBase + (size_t)srow[i] * 1024 + kt * 32 + scol[i],
                &sB[buf * 4096 + i * 2048 + t * 8]);
  };

  auto rd = [&](const bf16* s, int row) -> bf16x8 {
    const int phys = (row * 64 + g * 16) ^ (((row >> 1) & 7) << 4);
    return *(const bf16x8*)((const char*)s + phys);
  };

  const int wr = w >> 1, wc = w & 1;

  stage(0, 0);
  int buf = 0;
#pragma unroll 1
  for (int kt = 0; kt < 32; ++kt) {
    __builtin_amdgcn_s_barrier();            // all waves done reading buf^1's old tile
    if (kt < 31) {
      stage(buf ^ 1, kt + 1);                // 8 outstanding
      asm volatile("s_waitcnt vmcnt(4)" ::: "memory");   // tile kt landed; kt+1 in flight
    } else {
      asm volatile("s_waitcnt vmcnt(0)" ::: "memory");
    }
    __builtin_amdgcn_s_barrier();            // tile kt visible to all waves

    const bf16* tA = sA + buf * 4096;
    const bf16* tB = sB + buf * 4096;
    bf16x8 af[4], bfr[4];
#pragma unroll
    for (int mi = 0; mi < 4; ++mi) af[mi] = rd(tA, wr * 64 + mi * 16 + c);
#pragma unroll
    for (int ni = 0; ni < 4; ++ni) bfr[ni] = rd(tB, wc * 64 + ni * 16 + c);
    __builtin_amdgcn_s_setprio(1);
#pragma unroll
    for (int mi = 0; mi < 4; ++mi)
#pragma unroll
      for (int ni = 0; ni < 4; ++ni)
        acc[mi][ni] = MFMA16(af[mi], bfr[ni], acc[mi][ni]);
    __builtin_amdgcn_s_setprio(0);
    buf ^= 1;
  }
}

// T1: XCD-chunked bijective swizzle (nwg % 8 == 0). Physical block b runs on
// XCD b%8; logical id (b&7)*(nwg/8) + b>>3 gives each XCD a CONTIGUOUS logical
// chunk -> same-XCD blocks share bm (A-panel) and keep the 2MB weight panel hot
// in that XCD's 4MB L2, instead of every A-tile being fetched into all 8 L2s.
__device__ __forceinline__ int xcd_swz(int b, int nwg) {
  return (b & 7) * (nwg >> 3) + (b >> 3);
}

// QKV fused: 1536 blocks (z*512 + bm*8 + bn after swizzle). z==2 writes V^T.
__global__ __launch_bounds__(256) void qkv_gemm128(
    const bf16* __restrict__ qx, const bf16* __restrict__ kx, const bf16* __restrict__ vx,
    const bf16* __restrict__ wqb, const bf16* __restrict__ wkb, const bf16* __restrict__ wvb,
    const float* __restrict__ bq, const float* __restrict__ bk, const float* __restrict__ bv,
    bf16* __restrict__ qp, bf16* __restrict__ kp, bf16* __restrict__ vt, float qscale)
{
  __shared__ bf16 sA[2 * 4096];
  __shared__ bf16 sB[2 * 4096];
  const int l = xcd_swz(blockIdx.x, 1536);
  const int z = l >> 9;
  const int bm = (l & 511) >> 3, bn = l & 7;
  const bf16* A    = z == 0 ? qx  : z == 1 ? kx  : vx;
  const bf16* Bm   = z == 0 ? wqb : z == 1 ? wkb : wvb;
  const float* bias = z == 0 ? bq : z == 1 ? bk : bv;

  f32x4 acc[4][4] = {};
  gemm128_core(A + (size_t)(bm * 128) * 1024, Bm + (size_t)(bn * 128) * 1024, sA, sB, acc);

  const int t = threadIdx.x, lane = t & 63, w = t >> 6;
  const int wr = w >> 1, wc = w & 1, c = lane & 15, g = lane >> 4;
  const float sc = z == 0 ? qscale : 1.0f;
  bf16* Cb = z == 0 ? qp : kp;
#pragma unroll
  for (int ni = 0; ni < 4; ++ni) {
    const int col = bn * 128 + wc * 64 + ni * 16 + c;
    const float bvv = bias[col];
#pragma unroll
    for (int mi = 0; mi < 4; ++mi) {
#pragma unroll
      for (int r4 = 0; r4 < 4; ++r4) {
        const int row = bm * 128 + wr * 64 + mi * 16 + g * 4 + r4;
        const float val = (acc[mi][ni][r4] + bvv) * sc;
        if (z == 2) {
          const int bb = row >> 11, s = row & 2047;
          vt[((size_t)(bb * 1024 + col)) * 2048 + s] = (bf16)val;
        } else {
          Cb[(size_t)row * 1024 + col] = (bf16)val;
        }
      }
    }
  }
}

// O-projection: f32 output. 512 blocks (bm*8 + bn after swizzle).
__global__ __launch_bounds__(256) void out_gemm128(
    const bf16* __restrict__ A, const bf16* __restrict__ Bm,
    const float* __restrict__ bias, float* __restrict__ Cout)
{
  __shared__ bf16 sA[2 * 4096];
  __shared__ bf16 sB[2 * 4096];
  const int l = xcd_swz(blockIdx.x, 512);
  const int bm = l >> 3, bn = l & 7;

  f32x4 acc[4][4] = {};
  gemm128_core(A + (size_t)(bm * 128) * 1024, Bm + (size_t)(bn * 128) * 1024, sA, sB, acc);

  const int t = threadIdx.x, lane = t & 63, w = t >> 6;
  const int wr = w >> 1, wc = w & 1, c = lane & 15, g = lane >> 4;
#pragma unroll
  for (int ni = 0; ni < 4; ++ni) {
    const int col = bn * 128 + wc * 64 + ni * 16 + c;
    const float bvv = bias[col];
#pragma unroll
    for (int mi = 0; mi < 4; ++mi) {
#pragma unroll
      for (int r4 = 0; r4 < 4; ++r4) {
        const int row = bm * 128 + wr * 64 + mi * 16 + g * 4 + r4;
        Cout[(size_t)row * 1024 + col] = acc[mi][ni][r4] + bvv;
      }
    }
  }
}

// ---------------- flash attention (R10 structure, unchanged — control) ------------
__global__ __launch_bounds__(256) void attn_kernel(
    const bf16* __restrict__ Qp, const bf16* __restrict__ Kp, const bf16* __restrict__ Vt,
    const float* __restrict__ maskf, bf16* __restrict__ Out)
{
  __shared__ bf16 sKV[2][64 * 128];

  const int bh = blockIdx.x;
  const int b = bh >> 4, h = bh & 15;
  const int t = threadIdx.x, lane = t & 63, w = t >> 6;
  const int q32 = lane & 31, hi = lane >> 5;
  const int q0 = blockIdx.y * 128 + w * 32;

  const char* kBase = (const char*)(Kp + (size_t)(b * 2048) * 1024 + h * 64);
  const char* vBase = (const char*)(Vt + (size_t)(bh * 64) * 2048);

  // kt-uniform staging pointers: swizzle decode once; per-kt is 4 pointer adds.
  const char* srcp[4];
  int strd[4];
#pragma unroll
  for (int j = 0; j < 4; ++j) {
    const int P = j * 4096 + t * 16;
    const int L = P ^ (((P >> 8) & 15) << 4);
    const int row = L >> 8;          // 0..63
    const int off = L & 255;
    if (off < 128) { srcp[j] = kBase + (size_t)row * 2048 + off;         strd[j] = 131072; }
    else           { srcp[j] = vBase + (size_t)row * 4096 + (off - 128); strd[j] = 128; }
  }
  auto stageKV = [&](int buf) {
#pragma unroll
    for (int j = 0; j < 4; ++j)
      gld_lds16(srcp[j], (char*)sKV[buf] + j * 4096 + t * 16);
  };
  auto advKV = [&]() {
#pragma unroll
    for (int j = 0; j < 4; ++j) srcp[j] += strd[j];
  };

  bf16x8 qf[4];
  const bf16* qrow = Qp + (size_t)(b * 2048 + q0 + q32) * 1024 + h * 64;
#pragma unroll
  for (int ks = 0; ks < 4; ++ks)
    qf[ks] = *(const bf16x8*)&qrow[ks * 16 + hi * 8];

  float mrun = -1e30f, lrun = 0.f;
  f32x16 aco[2] = {};

  const float* mrow = maskf + b * 2048;

  stageKV(0);
  advKV();
  __syncthreads();
  int cur = 0;
  for (int kt = 0; kt < 32; ++kt) {
    if (kt + 1 < 32) { stageKV(cur ^ 1); advKV(); }

    // ---- S^T C-init = f32 additive mask (pure loads) ----
    f32x16 st[2];
#pragma unroll
    for (int kf = 0; kf < 2; ++kf)
#pragma unroll
      for (int q4 = 0; q4 < 4; ++q4) {
        const float4 mm = *(const float4*)&mrow[kt * 64 + kf * 32 + q4 * 8 + hi * 4];
        st[kf][q4 * 4 + 0] = mm.x;
        st[kf][q4 * 4 + 1] = mm.y;
        st[kf][q4 * 4 + 2] = mm.z;
        st[kf][q4 * 4 + 3] = mm.w;
      }

    // ---- S^T += K Q^T ----
#pragma unroll
    for (int ks = 0; ks < 4; ++ks) {
      bf16x8 k0f, k1f;
      {
        const int row = q32;
        const int phys = row * 256 + ((ks * 32 + hi * 16) ^ ((row & 15) << 4));
        k0f = *(const bf16x8*)((const char*)sKV[cur] + phys);
      }
      {
        const int row = 32 + q32;
        const int phys = row * 256 + ((ks * 32 + hi * 16) ^ ((row & 15) << 4));
        k1f = *(const bf16x8*)((const char*)sKV[cur] + phys);
      }
      __builtin_amdgcn_s_setprio(1);
      st[0] = MFMA32(k0f, qf[ks], st[0]);
      st[1] = MFMA32(k1f, qf[ks], st[1]);
      __builtin_amdgcn_s_setprio(0);
    }

    // ---- online softmax: max3 tree, defer-max, tree sum ----
    float c0 = max3f(st[0][0], st[0][1], st[0][2]);
    c0 = max3f(c0, st[0][3], st[0][4]);
    c0 = max3f(c0, st[0][5], st[0][6]);
    c0 = fmaxf(c0, st[0][7]);
    float c1 = max3f(st[0][8], st[0][9], st[0][10]);
    c1 = max3f(c1, st[0][11], st[0][12]);
    c1 = max3f(c1, st[0][13], st[0][14]);
    c1 = fmaxf(c1, st[0][15]);
    float c2 = max3f(st[1][0], st[1][1], st[1][2]);
    c2 = max3f(c2, st[1][3], st[1][4]);
    c2 = max3f(c2, st[1][5], st[1][6]);
    c2 = fmaxf(c2, st[1][7]);
    float c3 = max3f(st[1][8], st[1][9], st[1][10]);
    c3 = max3f(c3, st[1][11], st[1][12]);
    c3 = max3f(c3, st[1][13], st[1][14]);
    c3 = fmaxf(c3, st[1][15]);
    float tmax = fmaxf(max3f(c0, c1, c2), c3);
    tmax = fmaxf(tmax, __shfl_xor(tmax, 32, 64));
    if (!__all(tmax <= mrun + 11.5f)) {   // defer-max: THR = 8*log2(e)
      const float mnew = fmaxf(mrun, tmax);
      const float sc = exp2f(mrun - mnew);
      mrun = mnew;
      lrun *= sc;
      aco[0] *= sc;
      aco[1] *= sc;
    }
    float rs0 = 0.f, rs1 = 0.f, rs2 = 0.f, rs3 = 0.f;
#pragma unroll
    for (int i = 0; i < 16; i += 4) {
      float p00 = exp2f(st[0][i] - mrun),     p01 = exp2f(st[0][i + 1] - mrun);
      float p02 = exp2f(st[0][i + 2] - mrun), p03 = exp2f(st[0][i + 3] - mrun);
      float p10 = exp2f(st[1][i] - mrun),     p11 = exp2f(st[1][i + 1] - mrun);
      float p12 = exp2f(st[1][i + 2] - mrun), p13 = exp2f(st[1][i + 3] - mrun);
      st[0][i] = p00; st[0][i + 1] = p01; st[0][i + 2] = p02; st[0][i + 3] = p03;
      st[1][i] = p10; st[1][i + 1] = p11; st[1][i + 2] = p12; st[1][i + 3] = p13;
      rs0 += p00 + p01; rs1 += p02 + p03;
      rs2 += p10 + p11; rs3 += p12 + p13;
    }
    float rs = (rs0 + rs1) + (rs2 + rs3);
    rs += __shfl_xor(rs, 32, 64);
    lrun += rs;

    // ---- P -> PV A-frags in-register (T12) ----
    bf16x8 pa[4];
#pragma unroll
    for (int kf = 0; kf < 2; ++kf) {
      u32 u[4][2];
#pragma unroll
      for (int g2 = 0; g2 < 4; ++g2) {
        asm("v_cvt_pk_bf16_f32 %0, %1, %2"
            : "=v"(u[g2][0]) : "v"(st[kf][4 * g2 + 0]), "v"(st[kf][4 * g2 + 1]));
        asm("v_cvt_pk_bf16_f32 %0, %1, %2"
            : "=v"(u[g2][1]) : "v"(st[kf][4 * g2 + 2]), "v"(st[kf][4 * g2 + 3]));
      }
      u32 d0 = u[0][0], d2 = u[1][0];
      asm("v_permlane32_swap_b32 %0, %1" : "+v"(d0), "+v"(d2));
      u32 d1 = u[0][1], d3 = u[1][1];
      asm("v_permlane32_swap_b32 %0, %1" : "+v"(d1), "+v"(d3));
      u32x4 ud = {d0, d1, d2, d3};
      pa[2 * kf] = __builtin_bit_cast(bf16x8, ud);
      u32 e0 = u[2][0], e2 = u[3][0];
      asm("v_permlane32_swap_b32 %0, %1" : "+v"(e0), "+v"(e2));
      u32 e1 = u[2][1], e3 = u[3][1];
      asm("v_permlane32_swap_b32 %0, %1" : "+v"(e1), "+v"(e3));
      u32x4 ue = {e0, e1, e2, e3};
      pa[2 * kf + 1] = __builtin_bit_cast(bf16x8, ue);
    }

    // ---- O^T += V^T P^T ----
#pragma unroll
    for (int kk = 0; kk < 4; ++kk) {
      bf16x8 vb0, vb1;
      {
        const int row = q32;
        const int phys = row * 256 + ((128 + kk * 32 + hi * 16) ^ ((row & 15) << 4));
        vb0 = *(const bf16x8*)((const char*)sKV[cur] + phys);
      }
      {
        const int row = 32 + q32;
        const int phys = row * 256 + ((128 + kk * 32 + hi * 16) ^ ((row & 15) << 4));
        vb1 = *(const bf16x8*)((const char*)sKV[cur] + phys);
      }
      __builtin_amdgcn_s_setprio(1);
      aco[0] = MFMA32(vb0, pa[kk], aco[0]);
      aco[1] = MFMA32(vb1, pa[kk], aco[1]);
      __builtin_amdgcn_s_setprio(0);
    }

    __syncthreads();
    cur ^= 1;
  }

  const float inv = 1.0f / lrun;
  bf16* orow = Out + (size_t)(b * 2048 + q0 + q32) * 1024 + h * 64;
#pragma unroll
  for (int dkf = 0; dkf < 2; ++dkf)
#pragma unroll
    for (int q4 = 0; q4 < 4; ++q4) {
      bf16x4 o;
#pragma unroll
      for (int r4 = 0; r4 < 4; ++r4)
        o[r4] = (bf16)(aco[dkf][q4 * 4 + r4] * inv);
      *(bf16x4*)&orow[dkf * 32 + q4 * 8 + hi * 4] = o;
    }
}

extern "C" void kernel_launch(void* const* d_in, const int* in_sizes, int n_in,
                              void* d_out, int out_size, void* d_ws, size_t ws_size,
                              hipStream_t stream) {
  const float* q  = (const float*)d_in[0];
  const float* k  = (const float*)d_in[1];
  const float* v  = (const float*)d_in[2];
  const int*  msk = (const int*)d_in[3];
  const float* wq = (const float*)d_in[4];
  const float* bq = (const float*)d_in[5];
  const float* wk = (const float*)d_in[6];
  const float* bk = (const float*)d_in[7];
  const float* wv = (const float*)d_in[8];
  const float* bv = (const float*)d_in[9];
  const float* wo = (const float*)d_in[10];
  const float* bo = (const float*)d_in[11];

  bf16* ws = (bf16*)d_ws;
  const size_t NEL = 8192ull * 1024ull;  // 8M elements
  bf16* qx  = ws;
  bf16* kx  = ws + NEL;
  bf16* vx  = ws + 2 * NEL;
  bf16* wqb = ws + 3 * NEL;
  bf16* wkb = wqb + 1048576;
  bf16* wvb = wkb + 1048576;
  bf16* wob = wvb + 1048576;
  bf16* qp  = wob + 1048576;
  bf16* kp  = qp + NEL;
  bf16* vt  = kp + NEL;
  float* mf = (float*)(vt + NEL);        // 8192 f32 additive mask
  bf16* ao  = vx;  // vx dead after V projection

  cast3_kernel<<<24576, 256, 0, stream>>>(q, k, v, qx, kx, vx);
  cast4_kernel<<<4096, 256, 0, stream>>>(wq, wk, wv, wo, wqb, wkb, wvb, wob);
  maskf_kernel<<<8, 256, 0, stream>>>(msk, mf);

  // Q pre-scale folds softmax 1/sqrt(DK) AND log2(e) for exp2-domain softmax.
  const float qscale = 0.125f * 1.44269504088896f;
  qkv_gemm128<<<1536, 256, 0, stream>>>(qx, kx, vx, wqb, wkb, wvb,
                                        bq, bk, bv, qp, kp, vt, qscale);
  attn_kernel<<<dim3(64, 16), 256, 0, stream>>>(qp, kp, vt, mf, ao);
  out_gemm128<<<512, 256, 0, stream>>>(ao, wob, bo, (float*)d_out);
}